// Round 1
// baseline (316.040 us; speedup 1.0000x reference)
//
#include <hip/hip_runtime.h>

// 2D DWT (db2, symmetric pad, pywt-compatible), barrier-free / LDS-free.
// x: (16,3,1024,1024) f32 -> cA, cH: (16,3,513,513) f32, concatenated in d_out.
//
// Each thread owns 8 contiguous columns (128 threads cover the row).
// Vertical pass: 4-row register carry (xp[2i..2i+3]), 2x float4 + 1x float2
//   (the float2 redundantly re-loads the left neighbor's last 2 columns --
//   L1/L2 hit, zero extra HBM -- so NO cross-thread exchange is needed).
// Horizontal pass: pure registers, 4 outputs/thread (+1 on the last lane).
// No __syncthreads anywhere: the compiler pipelines the next-row-pair
// prefetch across the whole horizontal phase and store stream.

#define N 1024
#define NOUT 513
#define TI 8                             // output rows per block
#define STRIPS ((NOUT + TI - 1) / TI)    // 65

__device__ __forceinline__ int refl(int p) {
    int r = p - 2;
    r = (r < 0) ? (-1 - r) : r;
    r = (r > N - 1) ? (2 * N - 1 - r) : r;
    return r;
}

__device__ __forceinline__ float4 comb4(float w0, const float4 a, float w1, const float4 b,
                                        float w2, const float4 c, float w3, const float4 d) {
    float4 r;
    r.x = fmaf(w0, a.x, fmaf(w1, b.x, fmaf(w2, c.x, w3 * d.x)));
    r.y = fmaf(w0, a.y, fmaf(w1, b.y, fmaf(w2, c.y, w3 * d.y)));
    r.z = fmaf(w0, a.z, fmaf(w1, b.z, fmaf(w2, c.z, w3 * d.z)));
    r.w = fmaf(w0, a.w, fmaf(w1, b.w, fmaf(w2, c.w, w3 * d.w)));
    return r;
}

__device__ __forceinline__ float2 comb2(float w0, const float2 a, float w1, const float2 b,
                                        float w2, const float2 c, float w3, const float2 d) {
    float2 r;
    r.x = fmaf(w0, a.x, fmaf(w1, b.x, fmaf(w2, c.x, w3 * d.x)));
    r.y = fmaf(w0, a.y, fmaf(w1, b.y, fmaf(w2, c.y, w3 * d.y)));
    return r;
}

__global__ __launch_bounds__(128, 4) void dwt2_nolds(const float* __restrict__ x,
                                                     float* __restrict__ out) {
    // reversed filter taps (true convolution)
    const float l0 =  0.48296291314469025f;
    const float l1 =  0.836516303737469f;
    const float l2 =  0.22414386804185735f;
    const float l3 = -0.12940952255092145f;
    const float h0 = -0.12940952255092145f;
    const float h1 = -0.22414386804185735f;
    const float h2 =  0.836516303737469f;
    const float h3 = -0.48296291314469025f;

    const int strip = blockIdx.x;
    const int img   = blockIdx.y;
    const int i0 = strip * TI;
    const int u  = threadIdx.x;          // 0..127
    const int c  = 8 * u;                // owned columns c..c+7
    const int ce = (u == 0) ? 0 : (c - 2);  // left-neighbor cols (u=0: dummy, fixed up)

    const float* xim = x + (size_t)img * N * N;
    const size_t plane = (size_t)NOUT * NOUT;
    float* cA = out + (size_t)img * plane;
    float* cH = out + ((size_t)48 + img) * plane;

    const int nrows = (NOUT - i0 < TI) ? (NOUT - i0) : TI;

    // prologue: xp rows 2*i0 .. 2*i0+3
    const float* p0 = xim + (size_t)refl(2 * i0)     * N;
    const float* p1 = xim + (size_t)refl(2 * i0 + 1) * N;
    const float* p2 = xim + (size_t)refl(2 * i0 + 2) * N;
    const float* p3 = xim + (size_t)refl(2 * i0 + 3) * N;

    float4 r0a = *reinterpret_cast<const float4*>(p0 + c);
    float4 r0b = *reinterpret_cast<const float4*>(p0 + c + 4);
    float2 r0e = *reinterpret_cast<const float2*>(p0 + ce);
    float4 r1a = *reinterpret_cast<const float4*>(p1 + c);
    float4 r1b = *reinterpret_cast<const float4*>(p1 + c + 4);
    float2 r1e = *reinterpret_cast<const float2*>(p1 + ce);
    float4 n0a = *reinterpret_cast<const float4*>(p2 + c);
    float4 n0b = *reinterpret_cast<const float4*>(p2 + c + 4);
    float2 n0e = *reinterpret_cast<const float2*>(p2 + ce);
    float4 n1a = *reinterpret_cast<const float4*>(p3 + c);
    float4 n1b = *reinterpret_cast<const float4*>(p3 + c + 4);
    float2 n1e = *reinterpret_cast<const float2*>(p3 + ce);

    for (int ii = 0; ii < nrows; ++ii) {
        const int i = i0 + ii;

        // ---- vertical transform (registers only) ----
        float4 vloA = comb4(l0, r0a, l1, r1a, l2, n0a, l3, n1a);
        float4 vloB = comb4(l0, r0b, l1, r1b, l2, n0b, l3, n1b);
        float2 plo  = comb2(l0, r0e, l1, r1e, l2, n0e, l3, n1e);
        float4 vhiA = comb4(h0, r0a, h1, r1a, h2, n0a, h3, n1a);
        float4 vhiB = comb4(h0, r0b, h1, r1b, h2, n0b, h3, n1b);
        float2 phi  = comb2(h0, r0e, h1, r1e, h2, n0e, h3, n1e);

        // left image edge: j=0 uses xp cols (1,0,0,1)
        if (u == 0) {
            plo = make_float2(vloA.y, vloA.x);
            phi = make_float2(vhiA.y, vhiA.x);
        }

        // ---- rotate carries, issue next-row-pair prefetch early ----
        r0a = n0a; r0b = n0b; r0e = n0e;
        r1a = n1a; r1b = n1b; r1e = n1e;
        if (ii + 1 < nrows) {
            const float* q0 = xim + (size_t)refl(2 * i + 4) * N;
            const float* q1 = xim + (size_t)refl(2 * i + 5) * N;
            n0a = *reinterpret_cast<const float4*>(q0 + c);
            n0b = *reinterpret_cast<const float4*>(q0 + c + 4);
            n0e = *reinterpret_cast<const float2*>(q0 + ce);
            n1a = *reinterpret_cast<const float4*>(q1 + c);
            n1b = *reinterpret_cast<const float4*>(q1 + c + 4);
            n1e = *reinterpret_cast<const float2*>(q1 + ce);
        }

        // ---- horizontal transform (registers only) + store ----
        // out col j = 4u+m needs vertical values at cols 2j-2 .. 2j+1
        float oA0 = fmaf(l0, plo.x,  fmaf(l1, plo.y,  fmaf(l2, vloA.x, l3 * vloA.y)));
        float oA1 = fmaf(l0, vloA.x, fmaf(l1, vloA.y, fmaf(l2, vloA.z, l3 * vloA.w)));
        float oA2 = fmaf(l0, vloA.z, fmaf(l1, vloA.w, fmaf(l2, vloB.x, l3 * vloB.y)));
        float oA3 = fmaf(l0, vloB.x, fmaf(l1, vloB.y, fmaf(l2, vloB.z, l3 * vloB.w)));
        float oH0 = fmaf(l0, phi.x,  fmaf(l1, phi.y,  fmaf(l2, vhiA.x, l3 * vhiA.y)));
        float oH1 = fmaf(l0, vhiA.x, fmaf(l1, vhiA.y, fmaf(l2, vhiA.z, l3 * vhiA.w)));
        float oH2 = fmaf(l0, vhiA.z, fmaf(l1, vhiA.w, fmaf(l2, vhiB.x, l3 * vhiB.y)));
        float oH3 = fmaf(l0, vhiB.x, fmaf(l1, vhiB.y, fmaf(l2, vhiB.z, l3 * vhiB.w)));

        float* pa = cA + (size_t)i * NOUT + 4 * u;
        float* ph = cH + (size_t)i * NOUT + 4 * u;
        pa[0] = oA0; pa[1] = oA1; pa[2] = oA2; pa[3] = oA3;
        ph[0] = oH0; ph[1] = oH1; ph[2] = oH2; ph[3] = oH3;

        // right image edge: j=512 uses xp cols (1022,1023,1023,1022)
        if (u == 127) {
            pa[4] = fmaf(l0, vloB.z, fmaf(l1, vloB.w, fmaf(l2, vloB.w, l3 * vloB.z)));
            ph[4] = fmaf(l0, vhiB.z, fmaf(l1, vhiB.w, fmaf(l2, vhiB.w, l3 * vhiB.z)));
        }
    }
}

extern "C" void kernel_launch(void* const* d_in, const int* in_sizes, int n_in,
                              void* d_out, int out_size, void* d_ws, size_t ws_size,
                              hipStream_t stream) {
    (void)in_sizes; (void)n_in; (void)d_ws; (void)ws_size; (void)out_size;
    const float* x = (const float*)d_in[0];
    float* out = (float*)d_out;
    dim3 grid(STRIPS, 48);    // 65 x 48 = 3120 blocks
    dim3 block(128);
    dwt2_nolds<<<grid, block, 0, stream>>>(x, out);
}